// Round 15
// baseline (57.145 us; speedup 1.0000x reference)
//
#include <hip/hip_runtime.h>
#include <hip/hip_fp16.h>

// Joint bilateral filter block — slice-ring LDS staging, 4-wave j-split.
// x (1,1,20,96,96) f32; guide_im (N,343) f32, N = 16*96*96 = 147456;
// out n = dd*9216 + h*96 + w uses x depths dd+1..dd+3, H/W zero-pad.
//
// History: r4/r9/r12/r14 (full-patch LDS tile, 50KB, 3 blk/CU = 12 waves/CU)
// all 51-53us regardless of staging cost / conflicts / pipelining -> limiter
// is waves/CU x phase overlap. r13 (no LDS): 548MB overfetch, 277us.
// This round: 4-deep slice ring (7KB/slice -> 28.7KB/block -> 5 blk/CU =
// 20 waves/CU). All waves on same slab, split by c1-row j (w3 takes j=3,4
// and stages only 1 row). conv2 acc per-wave in regs, one exchange at end.
// T14 staging split: global loads before compute, ds_write after.

#define NPATCH 147456
#define TPB     256         // 4 waves
#define PPB      64         // patches per block
#define NBLK   (NPATCH / PPB)   // 2304
#define RING_DW 1792        // dwords per slice buffer: 64 patches * 28
#define SLICE_ROWS 448      // 64 patches * 7 rows

typedef float f4u __attribute__((ext_vector_type(4), aligned(4)));
typedef float f2u __attribute__((ext_vector_type(2), aligned(4)));

// ---------------- Kernel A: domain branch (runs once, 1 block) --------------
__global__ __launch_bounds__(128) void domain_branch_kernel(
    const float* __restrict__ dn,
    const float* __restrict__ w1, const float* __restrict__ b1,
    const float* __restrict__ w2, const float* __restrict__ b2,
    float* __restrict__ dom_out)
{
    __shared__ float s_in[344];
    __shared__ float s_c1[128];
    const int t = threadIdx.x;
    for (int idx = t; idx < 343; idx += 128) s_in[idx] = dn[idx];
    __syncthreads();
    if (t < 125) {
        const int i = t / 25, j = (t / 5) % 5, k = t % 5;
        float acc = b1[0];
        const float* base = &s_in[i * 49 + j * 7 + k];
#pragma unroll
        for (int dz = 0; dz < 3; ++dz)
#pragma unroll
            for (int dy = 0; dy < 3; ++dy)
#pragma unroll
                for (int dx = 0; dx < 3; ++dx)
                    acc = fmaf(base[dz * 49 + dy * 7 + dx], w1[dz * 9 + dy * 3 + dx], acc);
        s_c1[t] = fmaxf(acc, 0.f);
    }
    __syncthreads();
    if (t < 27) {
        const int dz = t / 9, dy = (t / 3) % 3, dx = t % 3;
        float acc = b2[0];
#pragma unroll
        for (int u = 0; u < 3; ++u)
#pragma unroll
            for (int v = 0; v < 3; ++v)
#pragma unroll
                for (int q = 0; q < 3; ++q)
                    acc = fmaf(s_c1[(dz + u) * 25 + (dy + v) * 5 + (dx + q)],
                               w2[u * 9 + v * 3 + q], acc);
        dom_out[t] = fmaxf(acc, 0.f);
    }
}

// ---------------- helpers ----------------
__device__ __forceinline__ float h2f_lo(unsigned int q) {
    return __half2float(__ushort_as_half((unsigned short)(q & 0xffffu)));
}
__device__ __forceinline__ float h2f_hi(unsigned int q) {
    return __half2float(__ushort_as_half((unsigned short)(q >> 16)));
}
__device__ __forceinline__ unsigned int pkh(float lo, float hi) {
    return __builtin_bit_cast(unsigned int, __builtin_amdgcn_cvt_pkrtz(lo, hi));
}

struct RowF { f4u a; f2u b; float c; };
__device__ __forceinline__ RowF load7(const float* __restrict__ s) {
    RowF r;
    r.a = *reinterpret_cast<const f4u*>(s);
    r.b = *reinterpret_cast<const f2u*>(s + 4);
    r.c = s[6];
    return r;
}
__device__ __forceinline__ void write7(unsigned int* dst, const RowF& r) {
    uint4 q;
    q.x = pkh(r.a.x, r.a.y); q.y = pkh(r.a.z, r.a.w);
    q.z = pkh(r.b.x, r.b.y); q.w = pkh(r.c, 0.f);
    *reinterpret_cast<uint4*>(dst) = q;
}
__device__ __forceinline__ void unpack7(const uint4 q, float* d) {
    d[0] = h2f_lo(q.x); d[1] = h2f_hi(q.x);
    d[2] = h2f_lo(q.y); d[3] = h2f_hi(q.y);
    d[4] = h2f_lo(q.z); d[5] = h2f_hi(q.z);
    d[6] = h2f_lo(q.w);
}

// c1 row (i, J) + fused conv2 accumulation. s0/s1/s2 = this lane's base in
// the ring buffers holding slices i, i+1, i+2; i folds per unrolled caller.
template<int J>
__device__ __forceinline__ void crow(const unsigned int* __restrict__ s0,
                                     const unsigned int* __restrict__ s1,
                                     const unsigned int* __restrict__ s2,
                                     int i, const float* __restrict__ w1,
                                     float bb1, const float* __restrict__ w2,
                                     float (&a2)[3][3][3])
{
    float rw[3][3][7];
#pragma unroll
    for (int dy = 0; dy < 3; ++dy) {
        unpack7(*reinterpret_cast<const uint4*>(s0 + (J + dy) * 4), rw[0][dy]);
        unpack7(*reinterpret_cast<const uint4*>(s1 + (J + dy) * 4), rw[1][dy]);
        unpack7(*reinterpret_cast<const uint4*>(s2 + (J + dy) * 4), rw[2][dy]);
    }

    float c1r[5];
#pragma unroll
    for (int k = 0; k < 5; ++k) {
        float a = bb1;
#pragma unroll
        for (int u = 0; u < 3; ++u)
#pragma unroll
            for (int v = 0; v < 3; ++v)
#pragma unroll
                for (int w = 0; w < 3; ++w)
                    a = fmaf(rw[u][v][k + w], w1[u * 9 + v * 3 + w], a);
        c1r[k] = fmaxf(a, 0.f);
    }

    constexpr int DY0 = (J - 2 < 0) ? 0 : J - 2;
    constexpr int DY1 = (J < 2) ? J : 2;
#pragma unroll
    for (int dz2 = 0; dz2 < 3; ++dz2) {
        const int u2 = i - dz2;
        if (u2 >= 0 && u2 < 3) {
#pragma unroll
            for (int dy2 = DY0; dy2 <= DY1; ++dy2) {
                const int v2 = J - dy2;
#pragma unroll
                for (int dx2 = 0; dx2 < 3; ++dx2)
#pragma unroll
                    for (int q = 0; q < 3; ++q)
                        a2[dz2][dy2][dx2] = fmaf(c1r[dx2 + q],
                                                 w2[u2 * 9 + v2 * 3 + q],
                                                 a2[dz2][dy2][dx2]);
            }
        }
    }
}

// ---------------- Kernel B: range branch + bilateral combine ----------------
__global__ __launch_bounds__(TPB, 4) void jbf_main_kernel(
    const float* __restrict__ guide, const float* __restrict__ x,
    const float* __restrict__ w1, const float* __restrict__ b1,
    const float* __restrict__ w2, const float* __restrict__ b2,
    const float* __restrict__ dom, float* __restrict__ out)
{
    __shared__ unsigned int ring[4 * RING_DW];   // 28,672 B

    const int tid  = threadIdx.x;
    const int wid  = tid >> 6;      // wave 0..3
    const int lane = tid & 63;      // patch owned by this thread
    const int blk  = blockIdx.x;
    const int n    = blk * PPB + lane;

    // ---- wave 0: issue the 27 scattered x loads early ----
    float xv[27];
    if (wid == 0) {
        const int dd  = n / 9216;
        const int rem = n - dd * 9216;
        const int h   = rem / 96;
        const int w_  = rem - h * 96;
#pragma unroll
        for (int dz = 0; dz < 3; ++dz)
#pragma unroll
            for (int dy = 0; dy < 3; ++dy)
#pragma unroll
                for (int dx = 0; dx < 3; ++dx) {
                    const int yy = h - 1 + dy, xx = w_ - 1 + dx;
                    float v = 0.f;
                    if (yy >= 0 && yy < 96 && xx >= 0 && xx < 96)
                        v = x[(dd + 1 + dz) * 9216 + yy * 96 + xx];
                    xv[dz * 9 + dy * 3 + dx] = v;
                }
    }

    // ---- hoisted staging coordinates (row-per-thread; 448 rows/slice) ----
    const float* __restrict__ srcf = guide + (size_t)blk * (PPB * 343);
    const int p1 = tid / 7,  y1 = tid - p1 * 7;
    const int R2 = tid + TPB;
    const int p2 = R2 / 7,   y2 = R2 - p2 * 7;
    const bool has2 = (R2 < SLICE_ROWS);          // tid < 192 (waves 0..2)
    const float* __restrict__ srow1 = srcf + p1 * 343 + y1 * 7;
    const float* __restrict__ srow2 = srcf + p2 * 343 + y2 * 7;
    unsigned int* const d1 = ring + p1 * 28 + y1 * 4;
    unsigned int* const d2 = ring + p2 * 28 + y2 * 4;

    // ---- prologue: stage slices 0,1,2 into ring[0..2] ----
#pragma unroll
    for (int s = 0; s < 3; ++s) {
        RowF ra = load7(srow1 + s * 49);
        write7(d1 + s * RING_DW, ra);
        if (has2) {
            RowF rb = load7(srow2 + s * 49);
            write7(d2 + s * RING_DW, rb);
        }
    }
    __syncthreads();

    const float bb1 = b1[0];
    float a2[3][3][3];
#pragma unroll
    for (int a = 0; a < 3; ++a)
#pragma unroll
        for (int b = 0; b < 3; ++b)
#pragma unroll
            for (int c = 0; c < 3; ++c) a2[a][b][c] = 0.f;

    // ---- slab loop: stage-issue(slice i+3) / compute(slab i) / write ----
#pragma unroll
    for (int i = 0; i <= 4; ++i) {
        RowF ra, rb;
        if (i < 4) {
            ra = load7(srow1 + (i + 3) * 49);           // issue early (T14)
            if (has2) rb = load7(srow2 + (i + 3) * 49);
        }

        const unsigned int* s0 = ring + ((i + 0) & 3) * RING_DW + lane * 28;
        const unsigned int* s1 = ring + ((i + 1) & 3) * RING_DW + lane * 28;
        const unsigned int* s2 = ring + ((i + 2) & 3) * RING_DW + lane * 28;
        if      (wid == 0) crow<0>(s0, s1, s2, i, w1, bb1, w2, a2);
        else if (wid == 1) crow<1>(s0, s1, s2, i, w1, bb1, w2, a2);
        else if (wid == 2) crow<2>(s0, s1, s2, i, w1, bb1, w2, a2);
        else { crow<3>(s0, s1, s2, i, w1, bb1, w2, a2);
               crow<4>(s0, s1, s2, i, w1, bb1, w2, a2); }

        if (i < 4) {
            write7(d1 + ((i + 3) & 3) * RING_DW, ra);   // write late (T14)
            if (has2) write7(d2 + ((i + 3) & 3) * RING_DW, rb);
        }
        __syncthreads();
    }

    // ---- partials exchange (ring is dead -> alias as f32) ----
    float* part = reinterpret_cast<float*>(ring);       // 3*1728 f32 = 20.7 KB
    if (wid != 0) {
#pragma unroll
        for (int t = 0; t < 27; ++t)
            part[(wid - 1) * 1728 + lane * 27 + t] = a2[t / 9][(t / 3) % 3][t % 3];
    }
    __syncthreads();

    // ---- combine + bilateral (wave 0) ----
    if (wid == 0) {
        const float bb2 = b2[0];
        float num = 0.f, den = 0.f;
#pragma unroll
        for (int t = 0; t < 27; ++t) {
            float r2v = bb2 + a2[t / 9][(t / 3) % 3][t % 3]
                      + part[0 * 1728 + lane * 27 + t]
                      + part[1 * 1728 + lane * 27 + t]
                      + part[2 * 1728 + lane * 27 + t];
            r2v = fmaxf(r2v, 0.f);
            const float wt = fmaf(dom[t], r2v, 1e-10f);
            num = fmaf(wt, xv[t], num);
            den += wt;
        }
        out[n] = num / den;
    }
}

extern "C" void kernel_launch(void* const* d_in, const int* in_sizes, int n_in,
                              void* d_out, int out_size, void* d_ws, size_t ws_size,
                              hipStream_t stream) {
    const float* x     = (const float*)d_in[0];
    const float* dn    = (const float*)d_in[1];
    const float* guide = (const float*)d_in[2];
    const float* w1_d  = (const float*)d_in[3];
    const float* b1_d  = (const float*)d_in[4];
    const float* w2_d  = (const float*)d_in[5];
    const float* b2_d  = (const float*)d_in[6];
    const float* w1_r  = (const float*)d_in[7];
    const float* b1_r  = (const float*)d_in[8];
    const float* w2_r  = (const float*)d_in[9];
    const float* b2_r  = (const float*)d_in[10];
    float* out = (float*)d_out;
    float* dom = (float*)d_ws;   // 27 floats of scratch

    domain_branch_kernel<<<1, 128, 0, stream>>>(dn, w1_d, b1_d, w2_d, b2_d, dom);
    jbf_main_kernel<<<NBLK, TPB, 0, stream>>>(guide, x, w1_r, b1_r, w2_r,
                                              b2_r, dom, out);
}

// Round 16
// 56.142 us; speedup vs baseline: 1.0179x; 1.0179x over previous
//
#include <hip/hip_runtime.h>
#include <hip/hip_fp16.h>

// Joint bilateral filter block — 4-wave cooperative, thread-per-patch,
// row-aligned fp16 LDS tile; ONE SHARED COMPACT CONV BODY (runtime slab i,
// static J, segment table) to fit L1 I-cache.
// x (1,1,20,96,96) f32; guide_im (N,343) f32, N = 16*96*96 = 147456;
// out n = dd*9216 + h*96 + w uses x depths dd+1..dd+3, H/W zero-pad.
//
// History: r4/r9/r12/r14 (full-patch tile, per-wave template-unrolled conv,
// ~45KB code) all 51-53us with VALU<25%, LDS<10%, HBM<35% busy -> suspected
// I-cache thrash (12 waves walking 4 distinct ~10KB regions, 32KB L1I).
// r13 no-LDS: 548MB overfetch. r15 slice-ring: spill (cap=256/arg law).
// This round: all waves share one ~12KB body; balanced 7/7/6/5 split via
// segment (i,j0,j1) table; conv2 weight rows scalar-selected per segment.

#define NPATCH 147456
#define TPB     256        // 4 waves
#define PPB      64        // patches per block (one per lane, all waves share)
#define NBLK   (NPATCH / PPB)   // 2304
#define ROW_H     8        // halves per row: 7 data + 1 pad (16 B aligned)
#define PATCH_H 392        // 49 rows * 8 halves = 784 B per patch
#define PATCH_D 196        // dwords per patch
#define NROWS  (PPB * 49)  // 3136 rows per tile

typedef float f4u __attribute__((ext_vector_type(4), aligned(4)));
typedef float f2u __attribute__((ext_vector_type(2), aligned(4)));

// ---------------- Kernel A: domain branch (runs once, 1 block) --------------
__global__ __launch_bounds__(128) void domain_branch_kernel(
    const float* __restrict__ dn,
    const float* __restrict__ w1, const float* __restrict__ b1,
    const float* __restrict__ w2, const float* __restrict__ b2,
    float* __restrict__ dom_out)
{
    __shared__ float s_in[344];
    __shared__ float s_c1[128];
    const int t = threadIdx.x;
    for (int idx = t; idx < 343; idx += 128) s_in[idx] = dn[idx];
    __syncthreads();
    if (t < 125) {
        const int i = t / 25, j = (t / 5) % 5, k = t % 5;
        float acc = b1[0];
        const float* base = &s_in[i * 49 + j * 7 + k];
#pragma unroll
        for (int dz = 0; dz < 3; ++dz)
#pragma unroll
            for (int dy = 0; dy < 3; ++dy)
#pragma unroll
                for (int dx = 0; dx < 3; ++dx)
                    acc = fmaf(base[dz * 49 + dy * 7 + dx], w1[dz * 9 + dy * 3 + dx], acc);
        s_c1[t] = fmaxf(acc, 0.f);
    }
    __syncthreads();
    if (t < 27) {
        const int dz = t / 9, dy = (t / 3) % 3, dx = t % 3;
        float acc = b2[0];
#pragma unroll
        for (int u = 0; u < 3; ++u)
#pragma unroll
            for (int v = 0; v < 3; ++v)
#pragma unroll
                for (int q = 0; q < 3; ++q)
                    acc = fmaf(s_c1[(dz + u) * 25 + (dy + v) * 5 + (dx + q)],
                               w2[u * 9 + v * 3 + q], acc);
        dom_out[t] = fmaxf(acc, 0.f);
    }
}

// ---------------- helpers ----------------
__device__ __forceinline__ float h2f_lo(unsigned int q) {
    return __half2float(__ushort_as_half((unsigned short)(q & 0xffffu)));
}
__device__ __forceinline__ float h2f_hi(unsigned int q) {
    return __half2float(__ushort_as_half((unsigned short)(q >> 16)));
}
__device__ __forceinline__ unsigned int pkh(float lo, float hi) {
    return __builtin_bit_cast(unsigned int, __builtin_amdgcn_cvt_pkrtz(lo, hi));
}
__device__ __forceinline__ void unpack7(const uint4 q, float* d) {
    d[0] = h2f_lo(q.x); d[1] = h2f_hi(q.x);
    d[2] = h2f_lo(q.y); d[3] = h2f_hi(q.y);
    d[4] = h2f_lo(q.z); d[5] = h2f_hi(q.z);
    d[6] = h2f_lo(q.w);
}

// segment table: wave w runs segments [2w], [2w+1]: (i, j0, j1).
// {4,0,4}+dummy keeps the 7/7/6/5 balanced split of the 25 (i,j) tasks.
__device__ const int seg_tab[8][3] = {
    {0, 0, 4}, {1, 0, 1},    // wave 0: 7 tasks
    {1, 2, 4}, {2, 0, 3},    // wave 1: 7 tasks
    {2, 4, 4}, {3, 0, 4},    // wave 2: 6 tasks
    {4, 0, 4}, {0, 9, 0},    // wave 3: 5 tasks (+dummy, j0=9 -> no steps)
};

// ---------------- Kernel B: range branch + bilateral combine ----------------
__global__ __launch_bounds__(TPB, 3) void jbf_main_kernel(
    const float* __restrict__ guide, const float* __restrict__ x,
    const float* __restrict__ w1, const float* __restrict__ b1,
    const float* __restrict__ w2, const float* __restrict__ b2,
    const float* __restrict__ dom, float* __restrict__ out)
{
    // partials buffer aliases the (dead-by-then) patch tile: 50,176 B total
    union SM {
        unsigned short tile[PPB * PATCH_H];   // 50,176 B
        float part[3][PPB][27];               // 20,736 B
    };
    __shared__ SM sm;

    const int tid  = threadIdx.x;
    const int wid  = tid >> 6;      // wave 0..3
    const int lane = tid & 63;      // patch owned by this thread
    const int blk  = blockIdx.x;
    const int n    = blk * PPB + lane;

    // ============== stage 64 patches -> fp16 LDS, row-per-thread ===========
    {
        const float* __restrict__ srcf = guide + (size_t)blk * (PPB * 343);
        unsigned int* __restrict__ tdw = reinterpret_cast<unsigned int*>(sm.tile);

        int idx = tid;
        int cp = idx / 49, cr = idx - cp * 49;
        f4u a = *reinterpret_cast<const f4u*>(srcf + cp * 343 + cr * 7);
        f2u b = *reinterpret_cast<const f2u*>(srcf + cp * 343 + cr * 7 + 4);
        float c = srcf[cp * 343 + cr * 7 + 6];

#pragma unroll 1
        for (int rd = 0; rd < 12; ++rd) {          // stores rounds 0..11 (full)
            int nidx = idx + TPB;
            if (nidx > NROWS - 1) nidx = NROWS - 1;    // clamp (dup load, rd==11)
            const int np = nidx / 49, nr = nidx - np * 49;
            const float* s = srcf + np * 343 + nr * 7;
            f4u na = *reinterpret_cast<const f4u*>(s);
            f2u nb = *reinterpret_cast<const f2u*>(s + 4);
            float nc = s[6];

            uint4 q;
            q.x = pkh(a.x, a.y); q.y = pkh(a.z, a.w);
            q.z = pkh(b.x, b.y); q.w = pkh(c, 0.f);
            *reinterpret_cast<uint4*>(tdw + cp * PATCH_D + cr * 4) = q;

            idx = nidx; cp = np; cr = nr; a = na; b = nb; c = nc;
        }
        if (tid < NROWS - 12 * TPB) {              // round 12 partial: 64 rows
            uint4 q;
            q.x = pkh(a.x, a.y); q.y = pkh(a.z, a.w);
            q.z = pkh(b.x, b.y); q.w = pkh(c, 0.f);
            *reinterpret_cast<uint4*>(tdw + cp * PATCH_D + cr * 4) = q;
        }
    }
    __syncthreads();

    // ============ conv1+conv2: ONE shared body, 2 segments per wave ========
    const unsigned int* __restrict__ P =
        reinterpret_cast<const unsigned int*>(sm.tile) + lane * PATCH_D;
    const float bb1 = b1[0];

    float a2[3][3][3];
    {
        const float init = (wid == 0) ? b2[0] : 0.f;   // bias added exactly once
#pragma unroll
        for (int a = 0; a < 3; ++a)
#pragma unroll
            for (int b = 0; b < 3; ++b)
#pragma unroll
                for (int c = 0; c < 3; ++c) a2[a][b][c] = init;
    }

#pragma unroll 1
    for (int s = 0; s < 2; ++s) {
        const int ti = __builtin_amdgcn_readfirstlane(seg_tab[wid * 2 + s][0]);
        const int j0 = __builtin_amdgcn_readfirstlane(seg_tab[wid * 2 + s][1]);
        const int j1 = __builtin_amdgcn_readfirstlane(seg_tab[wid * 2 + s][2]);

        // per-segment conv2 weight rows (scalar loads; clamped if invalid)
        float w2r[3][9];
        bool  vz[3];
#pragma unroll
        for (int dz2 = 0; dz2 < 3; ++dz2) {
            const int u2 = ti - dz2;
            vz[dz2] = (u2 >= 0) && (u2 <= 2);
            const int ub = (u2 < 0) ? 0 : ((u2 > 2) ? 2 : u2);
#pragma unroll
            for (int m = 0; m < 9; ++m) w2r[dz2][m] = w2[ub * 9 + m];
        }

        const unsigned int* __restrict__ Pi = P + ti * 28;

#pragma unroll
        for (int J = 0; J <= 4; ++J) {
            if (J >= j0 && J <= j1) {
                float c1r[5] = {bb1, bb1, bb1, bb1, bb1};
#pragma unroll
                for (int u = 0; u < 3; ++u)
#pragma unroll
                    for (int v = 0; v < 3; ++v) {
                        const uint4 q = *reinterpret_cast<const uint4*>(
                            Pi + u * 28 + (J + v) * 4);
                        float d[7];
                        unpack7(q, d);
#pragma unroll
                        for (int k = 0; k < 5; ++k)
#pragma unroll
                            for (int w = 0; w < 3; ++w)
                                c1r[k] = fmaf(d[k + w], w1[u * 9 + v * 3 + w],
                                              c1r[k]);
                    }
#pragma unroll
                for (int k = 0; k < 5; ++k) c1r[k] = fmaxf(c1r[k], 0.f);

#pragma unroll
                for (int dz2 = 0; dz2 < 3; ++dz2) {
                    if (vz[dz2]) {
#pragma unroll
                        for (int v2 = 0; v2 < 3; ++v2) {
                            const int dy2 = J - v2;          // static
                            if (dy2 >= 0 && dy2 < 3) {
#pragma unroll
                                for (int dx2 = 0; dx2 < 3; ++dx2)
#pragma unroll
                                    for (int q = 0; q < 3; ++q)
                                        a2[dz2][dy2][dx2] =
                                            fmaf(c1r[dx2 + q],
                                                 w2r[dz2][v2 * 3 + q],
                                                 a2[dz2][dy2][dx2]);
                            }
                        }
                    }
                }
            }
        }
    }

    __syncthreads();     // all tile reads complete before aliasing as `part`

    if (wid != 0) {
#pragma unroll
        for (int t = 0; t < 27; ++t)
            sm.part[wid - 1][lane][t] = a2[t / 9][(t / 3) % 3][t % 3];
    }
    __syncthreads();

    // ===================== combine + bilateral (wave 0 only) ================
    if (wid == 0) {
        const int dd  = n / 9216;
        const int rem = n - dd * 9216;
        const int h   = rem / 96;
        const int w_  = rem - h * 96;

        float num = 0.f, den = 0.f;
#pragma unroll
        for (int dz = 0; dz < 3; ++dz)
#pragma unroll
            for (int dy = 0; dy < 3; ++dy)
#pragma unroll
                for (int dx = 0; dx < 3; ++dx) {
                    const int t = dz * 9 + dy * 3 + dx;
                    const float r2 = fmaxf(a2[dz][dy][dx] + sm.part[0][lane][t]
                                           + sm.part[1][lane][t]
                                           + sm.part[2][lane][t], 0.f);
                    const float wt = fmaf(dom[t], r2, 1e-10f);
                    const int yy = h - 1 + dy, xx = w_ - 1 + dx;
                    float xv = 0.f;
                    if (yy >= 0 && yy < 96 && xx >= 0 && xx < 96)
                        xv = x[(dd + 1 + dz) * 9216 + yy * 96 + xx];
                    num = fmaf(wt, xv, num);
                    den += wt;
                }
        out[n] = num / den;
    }
}

extern "C" void kernel_launch(void* const* d_in, const int* in_sizes, int n_in,
                              void* d_out, int out_size, void* d_ws, size_t ws_size,
                              hipStream_t stream) {
    const float* x     = (const float*)d_in[0];
    const float* dn    = (const float*)d_in[1];
    const float* guide = (const float*)d_in[2];
    const float* w1_d  = (const float*)d_in[3];
    const float* b1_d  = (const float*)d_in[4];
    const float* w2_d  = (const float*)d_in[5];
    const float* b2_d  = (const float*)d_in[6];
    const float* w1_r  = (const float*)d_in[7];
    const float* b1_r  = (const float*)d_in[8];
    const float* w2_r  = (const float*)d_in[9];
    const float* b2_r  = (const float*)d_in[10];
    float* out = (float*)d_out;
    float* dom = (float*)d_ws;   // 27 floats of scratch

    domain_branch_kernel<<<1, 128, 0, stream>>>(dn, w1_d, b1_d, w2_d, b2_d, dom);
    jbf_main_kernel<<<NBLK, TPB, 0, stream>>>(guide, x, w1_r, b1_r, w2_r,
                                              b2_r, dom, out);
}

// Round 17
// 46.113 us; speedup vs baseline: 1.2392x; 1.2175x over previous
//
#include <hip/hip_runtime.h>
#include <hip/hip_fp16.h>

// Joint bilateral filter block — 4-wave cooperative, thread-per-patch,
// row-aligned fp16 LDS tile; DEEP-BATCHED staging (all 39 global loads in
// flight per thread before any consumption).
// x (1,1,20,96,96) f32; guide_im (N,343) f32, N = 16*96*96 = 147456;
// out n = dd*9216 + h*96 + w uses x depths dd+1..dd+3, H/W zero-pad.
//
// History: r4/r9/r12/r14/r16 all 51-56us. Little's-law diagnosis: staging
// kept only ~4 loads/wave in flight -> ~3KB/CU outstanding -> ~2.1 TB/s
// chip-wide (measured!) regardless of everything else. This round: 2-pass
// staging, 13 rows' loads (91 VGPR landing) issued before any convert/write,
// sched_barrier(0) between passes. Conv = r9 exactly. (256,2) cap 128;
// LDS 50KB keeps 3 blocks/CU resident.

#define NPATCH 147456
#define TPB     256        // 4 waves
#define PPB      64        // patches per block (one per lane, all waves share)
#define NBLK   (NPATCH / PPB)   // 2304
#define ROW_H     8        // halves per row: 7 data + 1 pad (16 B aligned)
#define PATCH_H 392        // 49 rows * 8 halves = 784 B per patch
#define PATCH_D 196        // dwords per patch
#define NROWS  (PPB * 49)  // 3136 rows per tile
#define NRD      13        // staging rounds: 12 full + 1 partial (64 rows)

typedef float f4u __attribute__((ext_vector_type(4), aligned(4)));
typedef float f2u __attribute__((ext_vector_type(2), aligned(4)));

// ---------------- Kernel A: domain branch (runs once, 1 block) --------------
__global__ __launch_bounds__(128) void domain_branch_kernel(
    const float* __restrict__ dn,
    const float* __restrict__ w1, const float* __restrict__ b1,
    const float* __restrict__ w2, const float* __restrict__ b2,
    float* __restrict__ dom_out)
{
    __shared__ float s_in[344];
    __shared__ float s_c1[128];
    const int t = threadIdx.x;
    for (int idx = t; idx < 343; idx += 128) s_in[idx] = dn[idx];
    __syncthreads();
    if (t < 125) {
        const int i = t / 25, j = (t / 5) % 5, k = t % 5;
        float acc = b1[0];
        const float* base = &s_in[i * 49 + j * 7 + k];
#pragma unroll
        for (int dz = 0; dz < 3; ++dz)
#pragma unroll
            for (int dy = 0; dy < 3; ++dy)
#pragma unroll
                for (int dx = 0; dx < 3; ++dx)
                    acc = fmaf(base[dz * 49 + dy * 7 + dx], w1[dz * 9 + dy * 3 + dx], acc);
        s_c1[t] = fmaxf(acc, 0.f);
    }
    __syncthreads();
    if (t < 27) {
        const int dz = t / 9, dy = (t / 3) % 3, dx = t % 3;
        float acc = b2[0];
#pragma unroll
        for (int u = 0; u < 3; ++u)
#pragma unroll
            for (int v = 0; v < 3; ++v)
#pragma unroll
                for (int q = 0; q < 3; ++q)
                    acc = fmaf(s_c1[(dz + u) * 25 + (dy + v) * 5 + (dx + q)],
                               w2[u * 9 + v * 3 + q], acc);
        dom_out[t] = fmaxf(acc, 0.f);
    }
}

// ---------------- helpers ----------------
__device__ __forceinline__ float h2f_lo(unsigned int q) {
    return __half2float(__ushort_as_half((unsigned short)(q & 0xffffu)));
}
__device__ __forceinline__ float h2f_hi(unsigned int q) {
    return __half2float(__ushort_as_half((unsigned short)(q >> 16)));
}
__device__ __forceinline__ unsigned int pkh(float lo, float hi) {
    return __builtin_bit_cast(unsigned int, __builtin_amdgcn_cvt_pkrtz(lo, hi));
}

// Load row y of absolute z-slice zi (16B-aligned, 8-half rows) into d[0..6].
// One ds_read_b128. zi, y fold to compile-time constants after unrolling.
__device__ __forceinline__ void load_row(const unsigned int* __restrict__ P, float* d,
                                         int zi, int y) {
    const int d0 = zi * 28 + y * 4;        // dword offset, multiple of 4 -> 16B
    const uint4 q = *reinterpret_cast<const uint4*>(P + d0);
    d[0] = h2f_lo(q.x); d[1] = h2f_hi(q.x);
    d[2] = h2f_lo(q.y); d[3] = h2f_hi(q.y);
    d[4] = h2f_lo(q.z); d[5] = h2f_hi(q.z);
    d[6] = h2f_lo(q.w);
}

// Run conv1+fused-conv2 row-tasks (i,j) from (IB,JB) to (IE,JE) inclusive,
// in row-major task order, accumulating into a2 (partial).
template<int IB, int JB, int IE, int JE>
__device__ __forceinline__ void run_tasks(const unsigned int* __restrict__ P,
                                          const float* __restrict__ w1, float bb1,
                                          const float* __restrict__ w2,
                                          float (&a2)[3][3][3])
{
#pragma unroll
    for (int i = IB; i <= IE; ++i) {              // c1 z-slab (input slices i..i+2)
        float rw[3][3][7];                        // [u][y%3][k]
        const int j0 = (i == IB) ? JB : 0;
        const int j1 = (i == IE) ? JE : 4;
#pragma unroll
        for (int j = j0; j <= j1; ++j) {
            if (j == j0) {
#pragma unroll
                for (int u = 0; u < 3; ++u)
#pragma unroll
                    for (int dy = 0; dy < 3; ++dy)
                        load_row(P, rw[u][(j + dy) % 3], i + u, j + dy);
            } else {
#pragma unroll
                for (int u = 0; u < 3; ++u)
                    load_row(P, rw[u][(j + 2) % 3], i + u, j + 2);
            }

            // c1 row (i, j, k=0..4)
            float c1r[5];
#pragma unroll
            for (int k = 0; k < 5; ++k) {
                float a = bb1;
#pragma unroll
                for (int u = 0; u < 3; ++u)
#pragma unroll
                    for (int v = 0; v < 3; ++v) {
                        const float* rr = rw[u][(j + v) % 3];
#pragma unroll
                        for (int w = 0; w < 3; ++w)
                            a = fmaf(rr[k + w], w1[u * 9 + v * 3 + w], a);
                    }
                c1r[k] = fmaxf(a, 0.f);
            }

            // fused conv2 accumulation
#pragma unroll
            for (int dz2 = 0; dz2 < 3; ++dz2) {
                const int u2 = i - dz2;
                if (u2 >= 0 && u2 < 3) {
#pragma unroll
                    for (int v2 = 0; v2 < 3; ++v2) {
                        const int dy2 = j - v2;
                        if (dy2 >= 0 && dy2 < 3) {
#pragma unroll
                            for (int dx2 = 0; dx2 < 3; ++dx2)
#pragma unroll
                                for (int q = 0; q < 3; ++q)
                                    a2[dz2][dy2][dx2] =
                                        fmaf(c1r[dx2 + q],
                                             w2[u2 * 9 + v2 * 3 + q],
                                             a2[dz2][dy2][dx2]);
                        }
                    }
                }
            }
        }
    }
}

// ---------------- Kernel B: range branch + bilateral combine ----------------
__global__ __launch_bounds__(TPB, 2) void jbf_main_kernel(
    const float* __restrict__ guide, const float* __restrict__ x,
    const float* __restrict__ w1, const float* __restrict__ b1,
    const float* __restrict__ w2, const float* __restrict__ b2,
    const float* __restrict__ dom, float* __restrict__ out)
{
    // partials buffer aliases the (dead-by-then) patch tile: 50,176 B total
    union SM {
        unsigned short tile[PPB * PATCH_H];   // 50,176 B
        float part[3][PPB][27];               // 20,736 B
    };
    __shared__ SM sm;

    const int tid  = threadIdx.x;
    const int wid  = tid >> 6;      // wave 0..3
    const int lane = tid & 63;      // patch owned by this thread
    const int blk  = blockIdx.x;
    const int n    = blk * PPB + lane;

    // ========= stage 64 patches -> fp16 LDS: DEEP-BATCHED two-pass =========
    // PASS 1: issue ALL 13 rows' loads (39 global loads, 91 VGPR landing).
    // PASS 2: convert + one ds_write_b128 per row. sched_barrier(0) keeps
    // the loads above the consumers -> ~22 KB in flight per wave.
    {
        const float* __restrict__ srcf = guide + (size_t)blk * (PPB * 343);
        unsigned int* __restrict__ tdw = reinterpret_cast<unsigned int*>(sm.tile);

        f4u A[NRD]; f2u B[NRD]; float C[NRD];
#pragma unroll
        for (int rd = 0; rd < NRD; ++rd) {
            int idx = tid + rd * TPB;
            if (idx > NROWS - 1) idx = NROWS - 1;   // clamp (dup load, rd==12)
            const int p = idx / 49, r = idx - p * 49;
            const float* s = srcf + p * 343 + r * 7;
            A[rd] = *reinterpret_cast<const f4u*>(s);
            B[rd] = *reinterpret_cast<const f2u*>(s + 4);
            C[rd] = s[6];
        }
        __builtin_amdgcn_sched_barrier(0);          // do not sink loads below
#pragma unroll
        for (int rd = 0; rd < NRD; ++rd) {
            if (rd < 12 || tid < NROWS - 12 * TPB) {    // rd 12: 64 rows only
                const int idx = tid + rd * TPB;
                const int p = idx / 49, r = idx - p * 49;
                uint4 q;
                q.x = pkh(A[rd].x, A[rd].y); q.y = pkh(A[rd].z, A[rd].w);
                q.z = pkh(B[rd].x, B[rd].y); q.w = pkh(C[rd], 0.f);
                *reinterpret_cast<uint4*>(tdw + p * PATCH_D + r * 4) = q;
            }
        }
    }
    __syncthreads();

    // ===================== per-thread conv1+conv2 (4-way task split) ========
    const unsigned int* __restrict__ P =
        reinterpret_cast<const unsigned int*>(sm.tile) + lane * PATCH_D;
    const float bb1 = b1[0];

    float a2[3][3][3];
    {
        const float init = (wid == 0) ? b2[0] : 0.f;   // bias added exactly once
#pragma unroll
        for (int a = 0; a < 3; ++a)
#pragma unroll
            for (int b = 0; b < 3; ++b)
#pragma unroll
                for (int c = 0; c < 3; ++c) a2[a][b][c] = init;
    }

    if      (wid == 0) run_tasks<0, 0, 1, 1>(P, w1, bb1, w2, a2);  // 7 tasks
    else if (wid == 1) run_tasks<1, 2, 2, 3>(P, w1, bb1, w2, a2);  // 7 tasks
    else if (wid == 2) run_tasks<2, 4, 3, 4>(P, w1, bb1, w2, a2);  // 6 tasks
    else               run_tasks<4, 0, 4, 4>(P, w1, bb1, w2, a2);  // 5 tasks

    __syncthreads();     // all tile reads complete before aliasing as `part`

    if (wid != 0) {
#pragma unroll
        for (int t = 0; t < 27; ++t)
            sm.part[wid - 1][lane][t] = a2[t / 9][(t / 3) % 3][t % 3];
    }
    __syncthreads();

    // ===================== combine + bilateral (wave 0 only) ================
    if (wid == 0) {
        const int dd  = n / 9216;
        const int rem = n - dd * 9216;
        const int h   = rem / 96;
        const int w_  = rem - h * 96;

        float num = 0.f, den = 0.f;
#pragma unroll
        for (int dz = 0; dz < 3; ++dz)
#pragma unroll
            for (int dy = 0; dy < 3; ++dy)
#pragma unroll
                for (int dx = 0; dx < 3; ++dx) {
                    const int t = dz * 9 + dy * 3 + dx;
                    const float r2 = fmaxf(a2[dz][dy][dx] + sm.part[0][lane][t]
                                           + sm.part[1][lane][t]
                                           + sm.part[2][lane][t], 0.f);
                    const float wt = fmaf(dom[t], r2, 1e-10f);
                    const int yy = h - 1 + dy, xx = w_ - 1 + dx;
                    float xv = 0.f;
                    if (yy >= 0 && yy < 96 && xx >= 0 && xx < 96)
                        xv = x[(dd + 1 + dz) * 9216 + yy * 96 + xx];
                    num = fmaf(wt, xv, num);
                    den += wt;
                }
        out[n] = num / den;
    }
}

extern "C" void kernel_launch(void* const* d_in, const int* in_sizes, int n_in,
                              void* d_out, int out_size, void* d_ws, size_t ws_size,
                              hipStream_t stream) {
    const float* x     = (const float*)d_in[0];
    const float* dn    = (const float*)d_in[1];
    const float* guide = (const float*)d_in[2];
    const float* w1_d  = (const float*)d_in[3];
    const float* b1_d  = (const float*)d_in[4];
    const float* w2_d  = (const float*)d_in[5];
    const float* b2_d  = (const float*)d_in[6];
    const float* w1_r  = (const float*)d_in[7];
    const float* b1_r  = (const float*)d_in[8];
    const float* w2_r  = (const float*)d_in[9];
    const float* b2_r  = (const float*)d_in[10];
    float* out = (float*)d_out;
    float* dom = (float*)d_ws;   // 27 floats of scratch

    domain_branch_kernel<<<1, 128, 0, stream>>>(dn, w1_d, b1_d, w2_d, b2_d, dom);
    jbf_main_kernel<<<NBLK, TPB, 0, stream>>>(guide, x, w1_r, b1_r, w2_r,
                                              b2_r, dom, out);
}